// Round 1
// baseline (5723.850 us; speedup 1.0000x reference)
//
#include <hip/hip_runtime.h>
#include <hip/hip_bf16.h>
#include <cstdint>

#define DEV __device__ __forceinline__

DEV float fsig(float x) { return 1.f / (1.f + __expf(-x)); }
DEV float ftanh(float x) { return 1.f - 2.f / (1.f + __expf(2.f * x)); }

// ---------------------------------------------------------------------------
// Generic fp32 tiled GEMM: C[M,N] = act(A[M,K] @ B[K,N] + bias[N])
// act: 0 = none, 1 = tanh
// ---------------------------------------------------------------------------
__global__ __launch_bounds__(256)
void gemm_kernel(const float* __restrict__ A, const float* __restrict__ B,
                 const float* __restrict__ bias, float* __restrict__ C,
                 int M, int N, int K, int act) {
  __shared__ float As[16][65];
  __shared__ float Bs[16][64];
  const int tid = threadIdx.x;
  const int tx = tid & 15, ty = tid >> 4;
  const int row0 = blockIdx.y * 64, col0 = blockIdx.x * 64;
  float acc[4][4] = {};
  for (int kk = 0; kk < K; kk += 16) {
#pragma unroll
    for (int p = 0; p < 4; ++p) {
      int lin = p * 256 + tid;
      int r = lin >> 4, c = lin & 15;
      float v = 0.f;
      if (row0 + r < M && kk + c < K) v = A[(size_t)(row0 + r) * K + kk + c];
      As[c][r] = v;
    }
#pragma unroll
    for (int p = 0; p < 4; ++p) {
      int lin = p * 256 + tid;
      int r = lin >> 6, c = lin & 63;
      float v = 0.f;
      if (kk + r < K) v = B[(size_t)(kk + r) * N + col0 + c];
      Bs[r][c] = v;
    }
    __syncthreads();
#pragma unroll
    for (int k = 0; k < 16; ++k) {
      float a[4], b[4];
#pragma unroll
      for (int i = 0; i < 4; ++i) a[i] = As[k][ty + 16 * i];
#pragma unroll
      for (int j = 0; j < 4; ++j) b[j] = Bs[k][tx + 16 * j];
#pragma unroll
      for (int i = 0; i < 4; ++i)
#pragma unroll
        for (int j = 0; j < 4; ++j) acc[i][j] += a[i] * b[j];
    }
    __syncthreads();
  }
#pragma unroll
  for (int i = 0; i < 4; ++i) {
    int r = row0 + ty + 16 * i;
    if (r >= M) continue;
#pragma unroll
    for (int j = 0; j < 4; ++j) {
      int c = col0 + tx + 16 * j;
      float v = acc[i][j] + bias[c];
      if (act == 1) v = ftanh(v);
      C[(size_t)r * N + c] = v;
    }
  }
}

// ---------------------------------------------------------------------------
// Transpose: out[C,R] = in[R,C]^T
// ---------------------------------------------------------------------------
__global__ __launch_bounds__(256)
void transpose_kernel(const float* __restrict__ in, float* __restrict__ out,
                      int R, int C) {
  __shared__ float tile[32][33];
  const int bc = blockIdx.x * 32, br = blockIdx.y * 32;
  const int tx = threadIdx.x & 31, ty = threadIdx.x >> 5;  // ty in [0,8)
#pragma unroll
  for (int p = 0; p < 4; ++p) {
    int r = br + ty + 8 * p, c = bc + tx;
    if (r < R && c < C) tile[ty + 8 * p][tx] = in[(size_t)r * C + c];
  }
  __syncthreads();
#pragma unroll
  for (int p = 0; p < 4; ++p) {
    int c = bc + ty + 8 * p, r = br + tx;
    if (r < R && c < C) out[(size_t)c * R + r] = tile[tx][ty + 8 * p];
  }
}

// ---------------------------------------------------------------------------
// Embedding gather
// ---------------------------------------------------------------------------
__global__ void emb_kernel(const float* __restrict__ emb,
                           const int* __restrict__ text,
                           float* __restrict__ xe) {
  int s = blockIdx.x;
  int row = text[s];
  for (int k = threadIdx.x; k < 300; k += 256)
    xe[s * 300 + k] = emb[(size_t)row * 300 + k];
}

// ---------------------------------------------------------------------------
// Persistent multi-block GRU scan with weights in VGPRs.
// Cross-block step sync: per-step counter (release add / acquire spin, device
// scope). h exchanged through the output buffer itself (per-step-distinct
// rows -> no stale-cache hazard; loads done as relaxed agent-scope atomics).
// H: hidden size. NB: blocks per instance. Block = 1024 threads.
// ---------------------------------------------------------------------------
struct ScanDesc {
  const float* whhT;  // [3H][H] transposed Whh
  const float* bhh;   // [3H]
  const float* pre;   // [T][3H]  (x@Wih + bih, natural time order)
  float* out;         // h rows: out[pos*stride + off + 0..H)
  int* cnt;           // [T] step counters (zeroed per launch)
  int T;
  int dir;            // 0 fwd, 1 bwd
  int stride;
  int off;
};
struct ScanArgs { ScanDesc d[4]; };

template <int H, int NB>
__global__ __launch_bounds__(1024)
void scan_kernel(ScanArgs args) {
  constexpr int UPB = H / NB;      // hidden units per block (32)
  constexpr int TPU = 1024 / UPB;  // threads per unit (32)
  constexpr int KS = H / TPU;      // k elems per thread
  const ScanDesc d = args.d[blockIdx.x / NB];
  const int b = blockIdx.x % NB;
  const int tid = threadIdx.x;
  const int ul = tid / TPU, slice = tid % TPU;
  const int unit = b * UPB + ul;

  // preload weights: thread covers k = slice + TPU*j (coalesced, LDS-conflict-free)
  float wr[KS], wz[KS], wn[KS];
#pragma unroll
  for (int j = 0; j < KS; ++j) {
    int k = slice + TPU * j;
    wr[j] = d.whhT[(size_t)(0 * H + unit) * H + k];
    wz[j] = d.whhT[(size_t)(1 * H + unit) * H + k];
    wn[j] = d.whhT[(size_t)(2 * H + unit) * H + k];
  }
  float bhr = 0.f, bhz = 0.f, bhn = 0.f;
  if (slice == 0) {
    bhr = d.bhh[unit];
    bhz = d.bhh[H + unit];
    bhn = d.bhh[2 * H + unit];
  }

  __shared__ float hsh[H];
  const int T = d.T, dir = d.dir, stride = d.stride, off = d.off;

  for (int s = 0; s < T; ++s) {
    const int pos = dir ? (T - 1 - s) : s;
    if (s == 0) {
      if (tid < H) hsh[tid] = 0.f;
    } else {
      if (tid == 0) {
        while (__hip_atomic_load(&d.cnt[s - 1], __ATOMIC_ACQUIRE,
                                 __HIP_MEMORY_SCOPE_AGENT) < NB) {}
      }
      __syncthreads();
      const int ppos = dir ? (pos + 1) : (pos - 1);
      if (tid < H)
        hsh[tid] = __hip_atomic_load(&d.out[(size_t)ppos * stride + off + tid],
                                     __ATOMIC_RELAXED, __HIP_MEMORY_SCOPE_AGENT);
    }
    __syncthreads();

    float ar = 0.f, az = 0.f, an = 0.f;
#pragma unroll
    for (int j = 0; j < KS; ++j) {
      float h = hsh[slice + TPU * j];
      ar += wr[j] * h;
      az += wz[j] * h;
      an += wn[j] * h;
    }
#pragma unroll
    for (int m = TPU / 2; m >= 1; m >>= 1) {
      ar += __shfl_xor(ar, m, 64);
      az += __shfl_xor(az, m, 64);
      an += __shfl_xor(an, m, 64);
    }
    if (slice == 0) {
      const float* prow = d.pre + (size_t)pos * (3 * H);
      float hp = hsh[unit];
      float r = fsig(prow[unit] + ar + bhr);
      float z = fsig(prow[H + unit] + az + bhz);
      float n = ftanh(prow[2 * H + unit] + r * (an + bhn));
      d.out[(size_t)pos * stride + off + unit] = (1.f - z) * n + z * hp;
    }
    __syncthreads();
    if (tid == 0)
      __hip_atomic_fetch_add(&d.cnt[s], 1, __ATOMIC_RELEASE,
                             __HIP_MEMORY_SCOPE_AGENT);
  }
}

// ---------------------------------------------------------------------------
// Cross-modal attention (fused): scores->softmax->h_s_bar->relu products
// One block per t. Writes X_cm[t] = [h_v_t | h_s_t] (1024 wide).
// ---------------------------------------------------------------------------
__global__ __launch_bounds__(256)
void cma_kernel(const float* __restrict__ qv, const float* __restrict__ ksm,
                const float* __restrict__ cmav, const float* __restrict__ Hv,
                const float* __restrict__ Hs, float* __restrict__ Xcm) {
  const int t = blockIdx.x, tid = threadIdx.x;
  const int lane = tid & 63, wave = tid >> 6;
  __shared__ float qsh[512], vsh[512], wsm[32];
  qsh[tid] = qv[t * 512 + tid];
  qsh[256 + tid] = qv[t * 512 + 256 + tid];
  vsh[tid] = cmav[tid];
  vsh[256 + tid] = cmav[256 + tid];
  __syncthreads();
  for (int s = wave; s < 32; s += 4) {
    float p = 0.f;
#pragma unroll
    for (int j = 0; j < 8; ++j) {
      int c = lane + 64 * j;
      p += ftanh(qsh[c] + ksm[s * 512 + c]) * vsh[c];
    }
#pragma unroll
    for (int m = 32; m >= 1; m >>= 1) p += __shfl_xor(p, m, 64);
    if (lane == 0) wsm[s] = p;
  }
  __syncthreads();
  float mx = -1e30f;
  for (int s = 0; s < 32; ++s) mx = fmaxf(mx, wsm[s]);
  float sum = 0.f;
  for (int s = 0; s < 32; ++s) sum += __expf(wsm[s] - mx);
  float inv = 1.f / sum;
  __syncthreads();
  if (tid < 32) wsm[tid] = __expf(wsm[tid] - mx) * inv;
  __syncthreads();
#pragma unroll
  for (int rep = 0; rep < 2; ++rep) {
    int c = tid + 256 * rep;
    float acc = 0.f;
#pragma unroll
    for (int s = 0; s < 32; ++s) acc += wsm[s] * Hs[s * 512 + c];
    float hb = acc;
    float hv = fmaxf(Hv[(size_t)t * 512 + c], 0.f) * hb;
    float hs2 = fmaxf(hb, 0.f) * hv;
    Xcm[(size_t)t * 1024 + c] = hv;
    Xcm[(size_t)t * 1024 + 512 + c] = hs2;
  }
}

// ---------------------------------------------------------------------------
// Masked self-attention (fused): scores (j>=i) -> softmax -> att row.
// Writes X_si[i] = [h_r[i] | att[i]].
// ---------------------------------------------------------------------------
__global__ __launch_bounds__(256)
void selfatt_kernel(const float* __restrict__ q2, const float* __restrict__ k2,
                    const float* __restrict__ siv, const float* __restrict__ hr,
                    float* __restrict__ Xsi) {
  const int i = blockIdx.x, tid = threadIdx.x;
  const int lane = tid & 63, wave = tid >> 6;
  __shared__ float qsh[512], vsh[512], scr[512];
  qsh[tid] = q2[(size_t)i * 512 + tid];
  qsh[256 + tid] = q2[(size_t)i * 512 + 256 + tid];
  vsh[tid] = siv[tid];
  vsh[256 + tid] = siv[256 + tid];
  __syncthreads();
  for (int j = i + wave; j < 512; j += 4) {
    float p = 0.f;
#pragma unroll
    for (int r = 0; r < 8; ++r) {
      int c = lane + 64 * r;
      p += ftanh(qsh[c] + k2[(size_t)j * 512 + c]) * vsh[c];
    }
#pragma unroll
    for (int m = 32; m >= 1; m >>= 1) p += __shfl_xor(p, m, 64);
    if (lane == 0) scr[j] = p;
  }
  __syncthreads();
  float mx = -1e30f;
  for (int j = i; j < 512; ++j) mx = fmaxf(mx, scr[j]);
  float sum = 0.f;
  for (int j = i; j < 512; ++j) sum += __expf(scr[j] - mx);
  float inv = 1.f / sum;
  __syncthreads();
  for (int j = i + tid; j < 512; j += 256) scr[j] = __expf(scr[j] - mx) * inv;
  __syncthreads();
#pragma unroll
  for (int rep = 0; rep < 2; ++rep) {
    int c = tid + 256 * rep;
    float acc = 0.f;
    for (int j = i; j < 512; ++j) acc += scr[j] * hr[(size_t)j * 512 + c];
    Xsi[(size_t)i * 1024 + c] = hr[(size_t)i * 512 + c];
    Xsi[(size_t)i * 1024 + 512 + c] = acc;
  }
}

// ---------------------------------------------------------------------------
// h_o = sum over the 32 rows of H_s (softmax over singleton axis == 1.0)
// ---------------------------------------------------------------------------
__global__ void ho_kernel(const float* __restrict__ Hs, float* __restrict__ ho) {
  int c = blockIdx.x * 256 + threadIdx.x;
  float a = 0.f;
#pragma unroll
  for (int s = 0; s < 32; ++s) a += Hs[s * 512 + c];
  ho[c] = a;
}

__global__ void cat_kernel(const float* __restrict__ hd,
                           const float* __restrict__ ho,
                           float* __restrict__ cat) {
  int i = blockIdx.x, tid = threadIdx.x;
#pragma unroll
  for (int r = 0; r < 4; ++r) {
    int k = tid + 256 * r;
    cat[(size_t)i * 1024 + k] = (k < 512) ? hd[(size_t)i * 512 + k] : ho[k - 512];
  }
}

__global__ __launch_bounds__(256)
void score_kernel(const float* __restrict__ tmp, const float* __restrict__ cpv,
                  float* __restrict__ out) {
  const int i = blockIdx.x, tid = threadIdx.x;
  float p = tmp[(size_t)i * 512 + tid] * cpv[tid] +
            tmp[(size_t)i * 512 + 256 + tid] * cpv[256 + tid];
#pragma unroll
  for (int m = 32; m >= 1; m >>= 1) p += __shfl_xor(p, m, 64);
  __shared__ float wsum[4];
  if ((tid & 63) == 0) wsum[tid >> 6] = p;
  __syncthreads();
  if (tid == 0) {
    out[i] = wsum[0] + wsum[1] + wsum[2] + wsum[3];
    out[497 + i] = (float)i;  // window_starts as float32
  }
}

// ---------------------------------------------------------------------------
extern "C" void kernel_launch(void* const* d_in, const int* in_sizes, int n_in,
                              void* d_out, int out_size, void* d_ws,
                              size_t ws_size, hipStream_t stream) {
  const float* video = (const float*)d_in[0];
  const int* text = (const int*)d_in[1];
  const float* vp_W = (const float*)d_in[2];
  const float* vp_b = (const float*)d_in[3];
  const float* vWih = (const float*)d_in[4];
  const float* vWhh = (const float*)d_in[5];
  const float* vbih = (const float*)d_in[6];
  const float* vbhh = (const float*)d_in[7];
  const float* emb = (const float*)d_in[8];
  const float* tp_W = (const float*)d_in[9];
  const float* tp_b = (const float*)d_in[10];
  const float* tWih = (const float*)d_in[11];
  const float* tWhh = (const float*)d_in[12];
  const float* tbih = (const float*)d_in[13];
  const float* tbhh = (const float*)d_in[14];
  const float* cmaWq = (const float*)d_in[15];
  const float* cmabq = (const float*)d_in[16];
  const float* cmaWk = (const float*)d_in[17];
  const float* cmabk = (const float*)d_in[18];
  const float* cmav = (const float*)d_in[19];
  const float* cmWih = (const float*)d_in[20];
  const float* cmWhh = (const float*)d_in[21];
  const float* cmbih = (const float*)d_in[22];
  const float* cmbhh = (const float*)d_in[23];
  const float* siWq = (const float*)d_in[24];
  const float* sibq = (const float*)d_in[25];
  const float* siWk = (const float*)d_in[26];
  const float* sibk = (const float*)d_in[27];
  const float* siv = (const float*)d_in[28];
  const float* sgWih = (const float*)d_in[29];
  const float* sgWhh = (const float*)d_in[30];
  const float* sgbih = (const float*)d_in[31];
  const float* sgbhh = (const float*)d_in[32];
  // d_in[33..35] = wp_W1/wp_b1/wp_v: dead (softmax over singleton axis == 1)
  const float* cpW1 = (const float*)d_in[36];
  const float* cpb1 = (const float*)d_in[37];
  const float* cpv = (const float*)d_in[38];
  float* out = (float*)d_out;

  float* ws = (float*)d_ws;
  int* cnt = (int*)d_ws;  // 6 instances x 512 ints
  size_t off = 3072;
  auto alloc = [&](size_t n) {
    float* p = ws + off;
    off += (n + 3) & ~(size_t)3;
    return p;
  };
  float* x_v = alloc(512 * 512);
  float* x_emb = alloc(32 * 300);
  float* x_s = alloc(32 * 512);
  float* pre_v = alloc(2 * 512 * 768);
  float* pre_s = alloc(2 * 32 * 768);
  float* Hv = alloc(512 * 512);
  float* Hs = alloc(32 * 512);
  float* qv = alloc(512 * 512);
  float* ksb = alloc(32 * 512);
  float* Xcm = alloc(512 * 1024);
  float* pre_cm = alloc(512 * 1536);
  float* hr = alloc(512 * 512);
  float* q2 = alloc(512 * 512);
  float* k2 = alloc(512 * 512);
  float* Xsi = alloc(512 * 1024);
  float* pre_si = alloc(512 * 1536);
  float* hd = alloc(512 * 512);
  float* ho = alloc(512);
  float* cat = alloc(512 * 1024);
  float* tmpb = alloc(512 * 512);
  float* whhT_v = alloc(2 * 768 * 256);
  float* whhT_t = alloc(2 * 768 * 256);
  float* whhT_cm = alloc(1536 * 512);
  float* whhT_si = alloc(1536 * 512);

  hipMemsetAsync(d_ws, 0, 3072 * sizeof(int), stream);

  // weight transposes for register-resident scans
  transpose_kernel<<<dim3(24, 8), 256, 0, stream>>>(vWhh, whhT_v, 256, 768);
  transpose_kernel<<<dim3(24, 8), 256, 0, stream>>>(vWhh + 196608, whhT_v + 196608, 256, 768);
  transpose_kernel<<<dim3(24, 8), 256, 0, stream>>>(tWhh, whhT_t, 256, 768);
  transpose_kernel<<<dim3(24, 8), 256, 0, stream>>>(tWhh + 196608, whhT_t + 196608, 256, 768);
  transpose_kernel<<<dim3(48, 16), 256, 0, stream>>>(cmWhh, whhT_cm, 512, 1536);
  transpose_kernel<<<dim3(48, 16), 256, 0, stream>>>(sgWhh, whhT_si, 512, 1536);

  // projections + GRU input pre-activations
  gemm_kernel<<<dim3(8, 8), 256, 0, stream>>>(video, vp_W, vp_b, x_v, 512, 512, 1024, 0);
  gemm_kernel<<<dim3(12, 8), 256, 0, stream>>>(x_v, vWih, vbih, pre_v, 512, 768, 512, 0);
  gemm_kernel<<<dim3(12, 8), 256, 0, stream>>>(x_v, vWih + 393216, vbih + 768, pre_v + 393216, 512, 768, 512, 0);
  emb_kernel<<<32, 256, 0, stream>>>(emb, text, x_emb);
  gemm_kernel<<<dim3(8, 1), 256, 0, stream>>>(x_emb, tp_W, tp_b, x_s, 32, 512, 300, 0);
  gemm_kernel<<<dim3(12, 1), 256, 0, stream>>>(x_s, tWih, tbih, pre_s, 32, 768, 512, 0);
  gemm_kernel<<<dim3(12, 1), 256, 0, stream>>>(x_s, tWih + 393216, tbih + 768, pre_s + 24576, 32, 768, 512, 0);

  // video + text BiGRU scans (4 instances x 8 blocks)
  ScanArgs a1{};
  a1.d[0] = ScanDesc{whhT_v, vbhh, pre_v, Hv, cnt + 0, 512, 0, 512, 0};
  a1.d[1] = ScanDesc{whhT_v + 196608, vbhh + 768, pre_v + 393216, Hv, cnt + 512, 512, 1, 512, 256};
  a1.d[2] = ScanDesc{whhT_t, tbhh, pre_s, Hs, cnt + 1024, 32, 0, 512, 0};
  a1.d[3] = ScanDesc{whhT_t + 196608, tbhh + 768, pre_s + 24576, Hs, cnt + 1536, 32, 1, 512, 256};
  scan_kernel<256, 8><<<32, 1024, 0, stream>>>(a1);

  // cross-modal attention
  gemm_kernel<<<dim3(8, 8), 256, 0, stream>>>(Hv, cmaWq, cmabq, qv, 512, 512, 512, 0);
  gemm_kernel<<<dim3(8, 1), 256, 0, stream>>>(Hs, cmaWk, cmabk, ksb, 32, 512, 512, 0);
  cma_kernel<<<512, 256, 0, stream>>>(qv, ksb, cmav, Hv, Hs, Xcm);
  gemm_kernel<<<dim3(24, 8), 256, 0, stream>>>(Xcm, cmWih, cmbih, pre_cm, 512, 1536, 1024, 0);

  ScanArgs a2{};
  a2.d[0] = ScanDesc{whhT_cm, cmbhh, pre_cm, hr, cnt + 2048, 512, 0, 512, 0};
  a2.d[1] = a2.d[0]; a2.d[2] = a2.d[0]; a2.d[3] = a2.d[0];
  scan_kernel<512, 16><<<16, 1024, 0, stream>>>(a2);

  // masked self-attention
  gemm_kernel<<<dim3(8, 8), 256, 0, stream>>>(hr, siWq, sibq, q2, 512, 512, 512, 0);
  gemm_kernel<<<dim3(8, 8), 256, 0, stream>>>(hr, siWk, sibk, k2, 512, 512, 512, 0);
  selfatt_kernel<<<512, 256, 0, stream>>>(q2, k2, siv, hr, Xsi);
  gemm_kernel<<<dim3(24, 8), 256, 0, stream>>>(Xsi, sgWih, sgbih, pre_si, 512, 1536, 1024, 0);

  ScanArgs a3{};
  a3.d[0] = ScanDesc{whhT_si, sgbhh, pre_si, hd, cnt + 2560, 512, 0, 512, 0};
  a3.d[1] = a3.d[0]; a3.d[2] = a3.d[0]; a3.d[3] = a3.d[0];
  scan_kernel<512, 16><<<16, 1024, 0, stream>>>(a3);

  // scoring head
  ho_kernel<<<2, 256, 0, stream>>>(Hs, ho);
  cat_kernel<<<512, 256, 0, stream>>>(hd, ho, cat);
  gemm_kernel<<<dim3(8, 8), 256, 0, stream>>>(cat, cpW1, cpb1, tmpb, 512, 512, 1024, 1);
  score_kernel<<<497, 256, 0, stream>>>(tmpb, cpv, out);
}